// Round 12
// baseline (3919.384 us; speedup 1.0000x reference)
//
#include <hip/hip_runtime.h>
#include <math.h>

typedef _Float16 f16;
typedef f16 f16x8 __attribute__((ext_vector_type(8)));
typedef float f32x4 __attribute__((ext_vector_type(4)));

#define NTOT 3840
#define KP   3968          // 3840 neurons + 128 inputs
#define BATCH 32
#define TSTEPS 100
#define NIN 128
#define NWG 241            // 240 col-tile WGs (16 cols, 1024 thr) + 1 readout WG
#define RSTRIDE (BATCH*KP) // ushorts per r buffer (126,976)
#define BROW 7952          // LDS bytes per B row: 3968*2 + 16 pad

__device__ __forceinline__ bool is_dend(int k){
  return (k>=512 && k<1536) || (k>=2432 && k<3456);
}
__device__ __forceinline__ bool is_inh(int k){
  return (k>=1536 && k<1920) || (k>=3456 && k<3840);
}
__device__ __forceinline__ ushort f2h(float v){ f16 h=(f16)v; return *(ushort*)&h; }
__device__ __forceinline__ float h2f(ushort u){ f16 h=*(f16*)&u; return (float)h; }

// ---------- one-time: WT[n][k] = fp16(w_eff^T), mask derived analytically ----------
__global__ __launch_bounds__(256) void k_prep_w(const float* __restrict__ w_rec,
    const float* __restrict__ w_in, ushort* __restrict__ WT){
  __shared__ ushort tile[64][72];
  const int bid = blockIdx.x;
  const int kt = bid / 60, nt = bid % 60;
  const int k0 = kt*64, n0 = nt*64;
  const int t = threadIdx.x;
  const int tr = t>>2, tq = t&3;
  const int k = k0 + tr;
  const int cbase = n0 + tq*16;
  if (k < NTOT){
    const float sgn = is_inh(k) ? -1.f : 1.f;
    const bool rowSr  = (k>=512  && k<1536);
    const bool rowPfc = (k>=2432 && k<3456);
    #pragma unroll
    for (int q=0;q<4;q++){
      float4 w = *(const float4*)(w_rec + (size_t)k*NTOT + cbase + q*4);
      float v[4] = {sgn*fabsf(w.x), sgn*fabsf(w.y), sgn*fabsf(w.z), sgn*fabsf(w.w)};
      #pragma unroll
      for (int e=0;e<4;e++){
        const int n = cbase + q*4 + e;
        if (n==k || (rowSr && n<512) || (rowPfc && n>=1920 && n<2432)) v[e]=0.f;
        tile[tr][tq*16+q*4+e] = f2h(v[e]);
      }
    }
  } else {
    const float* src = w_in + (size_t)(k-NTOT)*NTOT + cbase;
    #pragma unroll
    for (int q=0;q<4;q++){
      float4 w = *(const float4*)(src + q*4);
      tile[tr][tq*16+q*4+0] = f2h(w.x);
      tile[tr][tq*16+q*4+1] = f2h(w.y);
      tile[tr][tq*16+q*4+2] = f2h(w.z);
      tile[tr][tq*16+q*4+3] = f2h(w.w);
    }
  }
  __syncthreads();
  const int n  = n0 + tr;
  const int kq = tq*16;
  uint u[8];
  #pragma unroll
  for (int q=0;q<8;q++)
    u[q] = (uint)tile[kq+2*q][tr] | ((uint)tile[kq+2*q+1][tr] << 16);
  uint4* dst = (uint4*)(WT + (size_t)n*KP + k0 + kq);
  dst[0] = make_uint4(u[0],u[1],u[2],u[3]);
  dst[1] = make_uint4(u[4],u[5],u[6],u[7]);
}

// ---------- init: rbuf[0] (x_0 appended), barrier area zeroed ----------
__global__ void k_init(const float* __restrict__ x, ushort* __restrict__ r0,
                       unsigned* __restrict__ bar){
  int i = blockIdx.x*blockDim.x + threadIdx.x;
  int nthr = gridDim.x*blockDim.x;
  for (int e=i; e<1024; e+=nthr) bar[e] = 0u;
  for (int e=i; e<BATCH*KP; e+=nthr){
    int b = e / KP, k = e % KP;
    float v = (k<NTOT) ? (is_dend(k)?0.5f:0.f) : x[b*NIN + (k-NTOT)];
    r0[e] = f2h(v);
  }
}

// ---------- persistent kernel: all 100 steps; B-slice in LDS; fence-free rotation ----------
// 241 WGs x 1024 thr (16 waves, 4/SIMD). WG<240: 16 cols; wave (bh,kw) = batch-half x K/8.
// K split: kw<4 -> 512 (16 MFMA steps), kw>=4 -> 480 (15 steps). Only 16x16x32 MFMA used.
// B (127 KB) in LDS once; r rotates through 101 fresh buffers (no fences, sc1 stores).
__global__ __launch_bounds__(1024,1) void k_run(
    const ushort* __restrict__ WTu, ushort* rbase,
    const float* __restrict__ noise, const float* __restrict__ x,
    const float* __restrict__ bvec, const float* __restrict__ d2s,
    const float* __restrict__ w_out, const float* __restrict__ b_out,
    float* __restrict__ out, unsigned* bar)
{
  __shared__ ushort Blds[16*BROW/2];       // 127,232 B
  __shared__ f32x4 red[7][2][64];          // 14,336 B
  __shared__ float pre_lds[32][16];        // 2,048 B
  const f16* WT = (const f16*)WTu;
  const int bid = blockIdx.x;
  const int tid = threadIdx.x;
  const int wv = tid>>6, l = tid&63, l15 = l&15, lh = l>>4;
  const int bh = wv&1, kw = wv>>1;         // kw 0..7
  const int kbase = (kw<4) ? (kw<<9) : (2048 + (kw-4)*480);
  const int nst   = (kw<4) ? 16 : 15;      // MFMA k-steps for this wave
  const int n0 = bid*16;
  const int ub = tid>>4, uc = tid&15;      // update: (batch, col), tid<512 only
  const int n  = n0 + uc;
  const float NS = 0.0063245553203367585f; // sqrt(2*0.2)*0.01

  // persistent per-thread state (tid<512: 1 column each)
  float hr=0.f, im=0.f, bv=0.f, dA=0.f, dB=0.f, al=0.f;
  bool cSR=false, cPFC=false, cME=false, dendF=false;
  if (bid < 240){
    if (tid < 512){
      bv = bvec[n];
      cSR  = (n0 < 512);
      cPFC = (n0 >= 1920 && n0 < 2432);
      cME  = (n0 >= 2432 && n0 < 3456);
      dendF = (n0>=512 && n0<1536) || cME;
      if (cSR){  dA=d2s[n];       dB=d2s[512+n]; }
      if (cPFC){ const int j=n-1920; dA=d2s[1024+j]; dB=d2s[1536+j]; }
      if (cME){
        const float LN10 = 2.302585092994046f;
        const float CEXP = 1.6989700043360187f/511.0f;
        const int j = n-2432;
        al = expf(-LN10*(1.0f + CEXP*(float)(j&511)));
      }
    }
    // ---- prologue: stage this WG's B-slice (16 rows x 3968 k) into LDS ----
    for (int c = tid; c < 16*496; c += 1024){
      const int row = c / 496;
      const int kc  = c - row*496;
      f16x8 v = *(const f16x8*)(WT + (size_t)(n0+row)*KP + kc*8);
      *(f16x8*)((char*)Blds + row*BROW + kc*16) = v;
    }
  }

  // WG 240: preload w_out into registers (lane l covers rows l*8..l*8+7)
  float wo[3][8];
  float bo0=0.f, bo1=0.f, bo2=0.f;
  if (bid == 240){
    #pragma unroll
    for (int o=0;o<3;o++)
      #pragma unroll
      for (int i=0;i<8;i++) wo[o][i] = w_out[(l*8+i)*3 + o];
    bo0 = b_out[0]; bo1 = b_out[1]; bo2 = b_out[2];
  }
  __syncthreads();

  // barrier bookkeeping (monotonic epochs, no resets)
  const int xg = bid & 7;
  const unsigned mycnt = (xg==0) ? 31u : 30u;
  unsigned* xcnt = bar + xg*32;            // per-group arrival (128B apart)
  unsigned* gcnt = bar + 512;              // global leader counter
  unsigned* gep  = bar + 544;              // global epoch (single release word)

  // per-wave invariant LDS base for B
  const char* bb = (const char*)Blds + l15*BROW + kbase*2 + lh*16;

  for (int t=0; t<TSTEPS; t++){
    const ushort* rcu = rbase + (size_t)t*RSTRIDE;
    ushort*       rnu = rbase + (size_t)(t+1)*RSTRIDE;
    const f16* rc = (const f16*)rcu;

    if (bid < 240){
      // ---- prefetch update-phase operands (tid<512; hidden under MFMA) ----
      float nz_pf = 0.f, cA = 0.f, cB = 0.f;
      if (tid < 512){
        nz_pf = noise[(size_t)t*BATCH*NTOT + ub*NTOT + n];
        if (cSR){
          cA = h2f(rcu[ub*KP + 512 +n]); cB = h2f(rcu[ub*KP + 1024+n]);
        } else if (cPFC){
          const int j = n-1920;
          cA = h2f(rcu[ub*KP + 2432+j]); cB = h2f(rcu[ub*KP + 2944+j]);
        }
      }

      // ---- MFMA: 16 cols x 16 batch x (512|480)-K per wave; B from LDS ----
      f32x4 acc; acc.x=0.f; acc.y=0.f; acc.z=0.f; acc.w=0.f;
      {
        const f16* pa = rc + (size_t)(bh*16+l15)*KP + kbase + lh*8;
        #pragma unroll 4
        for (int ks=0; ks<nst; ks++){
          f16x8 a = *(const f16x8*)(pa + ks*32);
          f16x8 b = *(const f16x8*)(bb + ks*64);
          acc = __builtin_amdgcn_mfma_f32_16x16x32_f16(a, b, acc, 0,0,0);
        }
      }
      if (kw > 0) red[kw-1][bh][l] = acc;
      __syncthreads();
      if (kw == 0){
        #pragma unroll
        for (int w=0;w<7;w++) acc += red[w][bh][l];
        #pragma unroll
        for (int rg=0;rg<4;rg++)
          pre_lds[bh*16 + lh*4 + rg][l15] = acc[rg];
      }
      __syncthreads();

      // ---- update (tid<512): one (batch, col); r store agent-scope sc1 ----
      if (tid < 512){
        float p = pre_lds[ub][uc] + bv;
        p += cA*dA + cB*dB;
        if (cME){
          im = (1.f-al)*im + al*fmaxf(p,0.f); p += im;
        }
        hr = 0.8f*hr + 0.2f*p + NS*nz_pf;
        const float rv = dendF ? (1.f/(1.f+expf(-hr))) : fmaxf(hr,0.f);
        __hip_atomic_store(&rnu[ub*KP + n], f2h(rv),
                           __ATOMIC_RELAXED, __HIP_MEMORY_SCOPE_AGENT);
      }
    } else {
      // ---- WG 240: lane-parallel readout + x staging ----
      if (wv < 3){
        #pragma unroll
        for (int q=0;q<32;q++){
          const int p = wv*32 + q;
          if (p < 96){
            const int b = p/3, o = p%3;
            f16x8 rv8 = *(const f16x8*)(rc + (size_t)b*KP + l*8);
            float s = 0.f;
            #pragma unroll
            for (int i=0;i<8;i++) s += (float)rv8[i] * wo[o][i];
            #pragma unroll
            for (int off=32; off; off>>=1) s += __shfl_down(s, off);
            if (l==0){
              const float bo = (o==0)?bo0:((o==1)?bo1:bo2);
              out[t*BATCH*3 + b*3 + o] = s + bo;
            }
          }
        }
      }
      if (t+1 < TSTEPS && tid < 256){
        const int b = tid>>3, j = (tid&7)*16;
        const float* xs = x + (size_t)(t+1)*BATCH*NIN + b*NIN + j;
        #pragma unroll
        for (int q=0;q<4;q++){
          float4 v = *(const float4*)(xs + q*4);
          uint u0 = (uint)f2h(v.x) | ((uint)f2h(v.y)<<16);
          uint u1 = (uint)f2h(v.z) | ((uint)f2h(v.w)<<16);
          uint* dst = (uint*)&rnu[b*KP + NTOT + j + q*4];
          __hip_atomic_store(dst,   u0, __ATOMIC_RELAXED, __HIP_MEMORY_SCOPE_AGENT);
          __hip_atomic_store(dst+1, u1, __ATOMIC_RELAXED, __HIP_MEMORY_SCOPE_AGENT);
        }
      }
    }

    // ---- fence-free grid barrier: single release word, direct poll ----
    if (t+1 < TSTEPS){
      __syncthreads();                       // drains vmcnt: sc1 stores at L3
      if (tid == 0){
        unsigned old = __hip_atomic_fetch_add(xcnt, 1u,
                          __ATOMIC_RELAXED, __HIP_MEMORY_SCOPE_AGENT);
        if (old == mycnt*(unsigned)(t+1) - 1u){
          unsigned g = __hip_atomic_fetch_add(gcnt, 1u,
                          __ATOMIC_RELAXED, __HIP_MEMORY_SCOPE_AGENT);
          if (g == 8u*(unsigned)(t+1) - 1u)
            __hip_atomic_store(gep, (unsigned)(t+1),
                          __ATOMIC_RELAXED, __HIP_MEMORY_SCOPE_AGENT);
        }
        while (__hip_atomic_load(gep, __ATOMIC_RELAXED,
                      __HIP_MEMORY_SCOPE_AGENT) < (unsigned)(t+1))
          __builtin_amdgcn_s_sleep(1);
        asm volatile("" ::: "memory");       // compiler barrier (no L2 inv needed)
      }
      __syncthreads();
    }
  }
}

extern "C" void kernel_launch(void* const* d_in, const int* in_sizes, int n_in,
                              void* d_out, int out_size, void* d_ws, size_t ws_size,
                              hipStream_t stream) {
  const float* x     = (const float*)d_in[0];   // [100,32,128]
  const float* noise = (const float*)d_in[1];   // [100,32,3840]
  const float* w_rec = (const float*)d_in[2];   // [3840,3840]
  const float* w_in  = (const float*)d_in[3];   // [128,3840]
  const float* bvec  = (const float*)d_in[4];   // [3840]
  const float* d2s   = (const float*)d_in[5];   // [2048]
  const float* w_out = (const float*)d_in[6];   // [512,3]
  const float* b_out = (const float*)d_in[7];   // [3]
  // d_in[8] = mask: derived analytically
  float* out = (float*)d_out;                   // [100,32,3]

  char* ws = (char*)d_ws;
  ushort*   WT    = (ushort*)(ws);              // 30,474,240 B
  ushort*   rbase = (ushort*)(ws + 30474240);   // 101 x 253,952 B = 25,649,152 B
  unsigned* bar   = (unsigned*)(ws + 56123392); //      4,096 B

  k_prep_w<<<3720,256,0,stream>>>(w_rec, w_in, WT);
  k_init<<<64,256,0,stream>>>(x, rbase, bar);
  k_run<<<NWG,1024,0,stream>>>(WT, rbase, noise, x, bvec, d2s,
                               w_out, b_out, out, bar);
}

// Round 13
// 1900.160 us; speedup vs baseline: 2.0627x; 2.0627x over previous
//
#include <hip/hip_runtime.h>
#include <math.h>

typedef _Float16 f16;
typedef f16 f16x8 __attribute__((ext_vector_type(8)));
typedef float f32x4 __attribute__((ext_vector_type(4)));

#define NTOT 3840
#define KP   3968          // 3840 neurons + 128 inputs
#define BATCH 32
#define TSTEPS 100
#define NIN 128
#define NWG 241            // 240 col-tile WGs (16 cols, 768 thr) + 1 readout WG
#define RSTRIDE (BATCH*KP) // ushorts per r buffer (126,976)
#define BROW 7952          // LDS bytes per B row: 3968*2 + 16 pad

__device__ __forceinline__ bool is_dend(int k){
  return (k>=512 && k<1536) || (k>=2432 && k<3456);
}
__device__ __forceinline__ bool is_inh(int k){
  return (k>=1536 && k<1920) || (k>=3456 && k<3840);
}
__device__ __forceinline__ ushort f2h(float v){ f16 h=(f16)v; return *(ushort*)&h; }
__device__ __forceinline__ float h2f(ushort u){ f16 h=*(f16*)&u; return (float)h; }

// ---------- one-time: WT[n][k] = fp16(w_eff^T), mask derived analytically ----------
__global__ __launch_bounds__(256) void k_prep_w(const float* __restrict__ w_rec,
    const float* __restrict__ w_in, ushort* __restrict__ WT){
  __shared__ ushort tile[64][72];
  const int bid = blockIdx.x;
  const int kt = bid / 60, nt = bid % 60;
  const int k0 = kt*64, n0 = nt*64;
  const int t = threadIdx.x;
  const int tr = t>>2, tq = t&3;
  const int k = k0 + tr;
  const int cbase = n0 + tq*16;
  if (k < NTOT){
    const float sgn = is_inh(k) ? -1.f : 1.f;
    const bool rowSr  = (k>=512  && k<1536);
    const bool rowPfc = (k>=2432 && k<3456);
    #pragma unroll
    for (int q=0;q<4;q++){
      float4 w = *(const float4*)(w_rec + (size_t)k*NTOT + cbase + q*4);
      float v[4] = {sgn*fabsf(w.x), sgn*fabsf(w.y), sgn*fabsf(w.z), sgn*fabsf(w.w)};
      #pragma unroll
      for (int e=0;e<4;e++){
        const int n = cbase + q*4 + e;
        if (n==k || (rowSr && n<512) || (rowPfc && n>=1920 && n<2432)) v[e]=0.f;
        tile[tr][tq*16+q*4+e] = f2h(v[e]);
      }
    }
  } else {
    const float* src = w_in + (size_t)(k-NTOT)*NTOT + cbase;
    #pragma unroll
    for (int q=0;q<4;q++){
      float4 w = *(const float4*)(src + q*4);
      tile[tr][tq*16+q*4+0] = f2h(w.x);
      tile[tr][tq*16+q*4+1] = f2h(w.y);
      tile[tr][tq*16+q*4+2] = f2h(w.z);
      tile[tr][tq*16+q*4+3] = f2h(w.w);
    }
  }
  __syncthreads();
  const int n  = n0 + tr;
  const int kq = tq*16;
  uint u[8];
  #pragma unroll
  for (int q=0;q<8;q++)
    u[q] = (uint)tile[kq+2*q][tr] | ((uint)tile[kq+2*q+1][tr] << 16);
  uint4* dst = (uint4*)(WT + (size_t)n*KP + k0 + kq);
  dst[0] = make_uint4(u[0],u[1],u[2],u[3]);
  dst[1] = make_uint4(u[4],u[5],u[6],u[7]);
}

// ---------- init: rbuf[0] (x_0 appended), barrier area zeroed ----------
__global__ void k_init(const float* __restrict__ x, ushort* __restrict__ r0,
                       unsigned* __restrict__ bar){
  int i = blockIdx.x*blockDim.x + threadIdx.x;
  int nthr = gridDim.x*blockDim.x;
  for (int e=i; e<1024; e+=nthr) bar[e] = 0u;
  for (int e=i; e<BATCH*KP; e+=nthr){
    int b = e / KP, k = e % KP;
    float v = (k<NTOT) ? (is_dend(k)?0.5f:0.f) : x[b*NIN + (k-NTOT)];
    r0[e] = f2h(v);
  }
}

// ---------- persistent kernel: all 100 steps; B-slice in LDS; fence-free rotation ----------
// 241 WGs x 768 thr (12 waves, 3/SIMD). WG<240: 16 cols; wave (bh,kw) = batch-half x K/6.
// K split: kw<4 -> 672 (21 MFMA steps), kw>=4 -> 640 (20 steps). Only 16x16x32 MFMA.
// B (127 KB) in LDS once; WG 240 reuses Blds for w_out. No fences; sc1 stores; r rotates.
__global__ __launch_bounds__(768,1) void k_run(
    const ushort* __restrict__ WTu, ushort* rbase,
    const float* __restrict__ noise, const float* __restrict__ x,
    const float* __restrict__ bvec, const float* __restrict__ d2s,
    const float* __restrict__ w_out, const float* __restrict__ b_out,
    float* __restrict__ out, unsigned* bar)
{
  __shared__ ushort Blds[16*BROW/2];       // 127,232 B (WG240: w_out stage)
  __shared__ f32x4 red[5][2][64];          // 10,240 B
  __shared__ float pre_lds[32][16];        // 2,048 B
  const f16* WT = (const f16*)WTu;
  const int bid = blockIdx.x;
  const int tid = threadIdx.x;
  const int wv = tid>>6, l = tid&63, l15 = l&15, lh = l>>4;
  const int bh = wv&1, kw = wv>>1;         // kw 0..5
  const int kbase = (kw<4) ? kw*672 : (2688 + (kw-4)*640);
  const int nst   = (kw<4) ? 21 : 20;      // MFMA k-steps for this wave
  const int n0 = bid*16;
  const int ub = tid>>4, uc = tid&15;      // update: (batch, col), tid<512 only
  const int n  = n0 + uc;
  const float NS = 0.0063245553203367585f; // sqrt(2*0.2)*0.01

  // persistent per-thread state (tid<512: 1 column each)
  float hr=0.f, im=0.f, bv=0.f, dA=0.f, dB=0.f, al=0.f;
  bool cSR=false, cPFC=false, cME=false, dendF=false;
  if (bid < 240){
    if (tid < 512){
      bv = bvec[n];
      cSR  = (n0 < 512);
      cPFC = (n0 >= 1920 && n0 < 2432);
      cME  = (n0 >= 2432 && n0 < 3456);
      dendF = (n0>=512 && n0<1536) || cME;
      if (cSR){  dA=d2s[n];       dB=d2s[512+n]; }
      if (cPFC){ const int j=n-1920; dA=d2s[1024+j]; dB=d2s[1536+j]; }
      if (cME){
        const float LN10 = 2.302585092994046f;
        const float CEXP = 1.6989700043360187f/511.0f;
        const int j = n-2432;
        al = expf(-LN10*(1.0f + CEXP*(float)(j&511)));
      }
    }
    // ---- prologue: stage this WG's B-slice (16 rows x 3968 k) into LDS ----
    for (int c = tid; c < 16*496; c += 768){
      const int row = c / 496;
      const int kc  = c - row*496;
      f16x8 v = *(const f16x8*)(WT + (size_t)(n0+row)*KP + kc*8);
      *(f16x8*)((char*)Blds + row*BROW + kc*16) = v;
    }
  } else {
    // WG 240: stage w_out (512x3 f32) + b_out into Blds (keeps VGPRs low everywhere)
    float* fB = (float*)Blds;
    for (int c = tid; c < 1536; c += 768) fB[c] = w_out[c];
    if (tid < 3) fB[1536+tid] = b_out[tid];
  }
  __syncthreads();

  // barrier bookkeeping (monotonic epochs, no resets)
  const int xg = bid & 7;
  const unsigned mycnt = (xg==0) ? 31u : 30u;
  unsigned* xcnt = bar + xg*32;            // per-group arrival (128B apart)
  unsigned* gcnt = bar + 512;              // global leader counter
  unsigned* gep  = bar + 544;              // global epoch (single release word)

  // per-wave invariant LDS base for B
  const char* bb = (const char*)Blds + l15*BROW + kbase*2 + lh*16;

  for (int t=0; t<TSTEPS; t++){
    const ushort* rcu = rbase + (size_t)t*RSTRIDE;
    ushort*       rnu = rbase + (size_t)(t+1)*RSTRIDE;
    const f16* rc = (const f16*)rcu;

    if (bid < 240){
      // ---- prefetch update-phase operands (tid<512; hidden under MFMA) ----
      float nz_pf = 0.f, cA = 0.f, cB = 0.f;
      if (tid < 512){
        nz_pf = noise[(size_t)t*BATCH*NTOT + ub*NTOT + n];
        if (cSR){
          cA = h2f(rcu[ub*KP + 512 +n]); cB = h2f(rcu[ub*KP + 1024+n]);
        } else if (cPFC){
          const int j = n-1920;
          cA = h2f(rcu[ub*KP + 2432+j]); cB = h2f(rcu[ub*KP + 2944+j]);
        }
      }

      // ---- MFMA: 16 cols x 16 batch x (672|640)-K per wave; B from LDS ----
      f32x4 acc; acc.x=0.f; acc.y=0.f; acc.z=0.f; acc.w=0.f;
      {
        const f16* pa = rc + (size_t)(bh*16+l15)*KP + kbase + lh*8;
        #pragma unroll 4
        for (int ks=0; ks<nst; ks++){
          f16x8 a = *(const f16x8*)(pa + ks*32);
          f16x8 b = *(const f16x8*)(bb + ks*64);
          acc = __builtin_amdgcn_mfma_f32_16x16x32_f16(a, b, acc, 0,0,0);
        }
      }
      if (kw > 0) red[kw-1][bh][l] = acc;
      __syncthreads();
      if (kw == 0){
        #pragma unroll
        for (int w=0;w<5;w++) acc += red[w][bh][l];
        #pragma unroll
        for (int rg=0;rg<4;rg++)
          pre_lds[bh*16 + lh*4 + rg][l15] = acc[rg];
      }
      __syncthreads();

      // ---- update (tid<512): one (batch, col); r store agent-scope sc1 ----
      if (tid < 512){
        float p = pre_lds[ub][uc] + bv;
        p += cA*dA + cB*dB;
        if (cME){
          im = (1.f-al)*im + al*fmaxf(p,0.f); p += im;
        }
        hr = 0.8f*hr + 0.2f*p + NS*nz_pf;
        const float rv = dendF ? (1.f/(1.f+expf(-hr))) : fmaxf(hr,0.f);
        __hip_atomic_store(&rnu[ub*KP + n], f2h(rv),
                           __ATOMIC_RELAXED, __HIP_MEMORY_SCOPE_AGENT);
      }
    } else {
      // ---- WG 240: lane-parallel readout (weights from LDS) + x staging ----
      const float* fB = (const float*)Blds;
      if (wv < 3){
        #pragma unroll
        for (int q=0;q<32;q++){
          const int p = wv*32 + q;
          const int b = p/3, o = p%3;
          f16x8 rv8 = *(const f16x8*)(rc + (size_t)b*KP + l*8);
          float s = 0.f;
          #pragma unroll
          for (int i=0;i<8;i++) s += (float)rv8[i] * fB[(l*8+i)*3 + o];
          #pragma unroll
          for (int off=32; off; off>>=1) s += __shfl_down(s, off);
          if (l==0) out[t*BATCH*3 + b*3 + o] = s + fB[1536+o];
        }
      }
      if (t+1 < TSTEPS && tid < 256){
        const int b = tid>>3, j = (tid&7)*16;
        const float* xs = x + (size_t)(t+1)*BATCH*NIN + b*NIN + j;
        #pragma unroll
        for (int q=0;q<4;q++){
          float4 v = *(const float4*)(xs + q*4);
          uint u0 = (uint)f2h(v.x) | ((uint)f2h(v.y)<<16);
          uint u1 = (uint)f2h(v.z) | ((uint)f2h(v.w)<<16);
          uint* dst = (uint*)&rnu[b*KP + NTOT + j + q*4];
          __hip_atomic_store(dst,   u0, __ATOMIC_RELAXED, __HIP_MEMORY_SCOPE_AGENT);
          __hip_atomic_store(dst+1, u1, __ATOMIC_RELAXED, __HIP_MEMORY_SCOPE_AGENT);
        }
      }
    }

    // ---- fence-free grid barrier: single release word, direct poll ----
    if (t+1 < TSTEPS){
      __syncthreads();                       // drains vmcnt: sc1 stores at L3
      if (tid == 0){
        unsigned old = __hip_atomic_fetch_add(xcnt, 1u,
                          __ATOMIC_RELAXED, __HIP_MEMORY_SCOPE_AGENT);
        if (old == mycnt*(unsigned)(t+1) - 1u){
          unsigned g = __hip_atomic_fetch_add(gcnt, 1u,
                          __ATOMIC_RELAXED, __HIP_MEMORY_SCOPE_AGENT);
          if (g == 8u*(unsigned)(t+1) - 1u)
            __hip_atomic_store(gep, (unsigned)(t+1),
                          __ATOMIC_RELAXED, __HIP_MEMORY_SCOPE_AGENT);
        }
        while (__hip_atomic_load(gep, __ATOMIC_RELAXED,
                      __HIP_MEMORY_SCOPE_AGENT) < (unsigned)(t+1))
          __builtin_amdgcn_s_sleep(1);
        asm volatile("" ::: "memory");       // compiler barrier (no L2 inv needed)
      }
      __syncthreads();
    }
  }
}

extern "C" void kernel_launch(void* const* d_in, const int* in_sizes, int n_in,
                              void* d_out, int out_size, void* d_ws, size_t ws_size,
                              hipStream_t stream) {
  const float* x     = (const float*)d_in[0];   // [100,32,128]
  const float* noise = (const float*)d_in[1];   // [100,32,3840]
  const float* w_rec = (const float*)d_in[2];   // [3840,3840]
  const float* w_in  = (const float*)d_in[3];   // [128,3840]
  const float* bvec  = (const float*)d_in[4];   // [3840]
  const float* d2s   = (const float*)d_in[5];   // [2048]
  const float* w_out = (const float*)d_in[6];   // [512,3]
  const float* b_out = (const float*)d_in[7];   // [3]
  // d_in[8] = mask: derived analytically
  float* out = (float*)d_out;                   // [100,32,3]

  char* ws = (char*)d_ws;
  ushort*   WT    = (ushort*)(ws);              // 30,474,240 B
  ushort*   rbase = (ushort*)(ws + 30474240);   // 101 x 253,952 B = 25,649,152 B
  unsigned* bar   = (unsigned*)(ws + 56123392); //      4,096 B

  k_prep_w<<<3720,256,0,stream>>>(w_rec, w_in, WT);
  k_init<<<64,256,0,stream>>>(x, rbase, bar);
  k_run<<<NWG,768,0,stream>>>(WT, rbase, noise, x, bvec, d2s,
                              w_out, b_out, out, bar);
}

// Round 14
// 1819.628 us; speedup vs baseline: 2.1539x; 1.0443x over previous
//
#include <hip/hip_runtime.h>
#include <math.h>

typedef _Float16 f16;
typedef f16 f16x8 __attribute__((ext_vector_type(8)));
typedef float f32x4 __attribute__((ext_vector_type(4)));

#define NTOT 3840
#define KP   3968          // 3840 neurons + 128 inputs
#define BATCH 32
#define TSTEPS 100
#define NIN 128
#define NWG 241            // 240 col-tile WGs (16 cols, 768 thr) + 1 readout WG
#define RSTRIDE (BATCH*KP) // ushorts per r buffer (126,976)
#define BROW 7952          // LDS bytes per B row: 3968*2 + 16 pad

__device__ __forceinline__ bool is_dend(int k){
  return (k>=512 && k<1536) || (k>=2432 && k<3456);
}
__device__ __forceinline__ bool is_inh(int k){
  return (k>=1536 && k<1920) || (k>=3456 && k<3840);
}
__device__ __forceinline__ ushort f2h(float v){ f16 h=(f16)v; return *(ushort*)&h; }
__device__ __forceinline__ float h2f(ushort u){ f16 h=*(f16*)&u; return (float)h; }

// ---------- one-time: WT[n][k] = fp16(w_eff^T), mask derived analytically ----------
__global__ __launch_bounds__(256) void k_prep_w(const float* __restrict__ w_rec,
    const float* __restrict__ w_in, ushort* __restrict__ WT){
  __shared__ ushort tile[64][72];
  const int bid = blockIdx.x;
  const int kt = bid / 60, nt = bid % 60;
  const int k0 = kt*64, n0 = nt*64;
  const int t = threadIdx.x;
  const int tr = t>>2, tq = t&3;
  const int k = k0 + tr;
  const int cbase = n0 + tq*16;
  if (k < NTOT){
    const float sgn = is_inh(k) ? -1.f : 1.f;
    const bool rowSr  = (k>=512  && k<1536);
    const bool rowPfc = (k>=2432 && k<3456);
    #pragma unroll
    for (int q=0;q<4;q++){
      float4 w = *(const float4*)(w_rec + (size_t)k*NTOT + cbase + q*4);
      float v[4] = {sgn*fabsf(w.x), sgn*fabsf(w.y), sgn*fabsf(w.z), sgn*fabsf(w.w)};
      #pragma unroll
      for (int e=0;e<4;e++){
        const int n = cbase + q*4 + e;
        if (n==k || (rowSr && n<512) || (rowPfc && n>=1920 && n<2432)) v[e]=0.f;
        tile[tr][tq*16+q*4+e] = f2h(v[e]);
      }
    }
  } else {
    const float* src = w_in + (size_t)(k-NTOT)*NTOT + cbase;
    #pragma unroll
    for (int q=0;q<4;q++){
      float4 w = *(const float4*)(src + q*4);
      tile[tr][tq*16+q*4+0] = f2h(w.x);
      tile[tr][tq*16+q*4+1] = f2h(w.y);
      tile[tr][tq*16+q*4+2] = f2h(w.z);
      tile[tr][tq*16+q*4+3] = f2h(w.w);
    }
  }
  __syncthreads();
  const int n  = n0 + tr;
  const int kq = tq*16;
  uint u[8];
  #pragma unroll
  for (int q=0;q<8;q++)
    u[q] = (uint)tile[kq+2*q][tr] | ((uint)tile[kq+2*q+1][tr] << 16);
  uint4* dst = (uint4*)(WT + (size_t)n*KP + k0 + kq);
  dst[0] = make_uint4(u[0],u[1],u[2],u[3]);
  dst[1] = make_uint4(u[4],u[5],u[6],u[7]);
}

// ---------- init: rbuf[0] (x_0 appended), barrier area zeroed ----------
__global__ void k_init(const float* __restrict__ x, ushort* __restrict__ r0,
                       unsigned* __restrict__ bar){
  int i = blockIdx.x*blockDim.x + threadIdx.x;
  int nthr = gridDim.x*blockDim.x;
  for (int e=i; e<1024; e+=nthr) bar[e] = 0u;
  for (int e=i; e<BATCH*KP; e+=nthr){
    int b = e / KP, k = e % KP;
    float v = (k<NTOT) ? (is_dend(k)?0.5f:0.f) : x[b*NIN + (k-NTOT)];
    r0[e] = f2h(v);
  }
}

// ---------- persistent kernel: all 100 steps; B-slice in LDS; fence-free rotation ----------
// 241 WGs x 768 thr (12 waves, 3/SIMD). WG<240: 16 cols; wave (bh,kw) = batch-half x K/6.
// K split: kw<4 -> 672 (21 MFMA steps), kw>=4 -> 640 (20). Hierarchical 2-level barrier
// (R9's proven design: <=30 pollers per line). No fences; sc1 stores; r rotates.
__global__ __launch_bounds__(768,1) void k_run(
    const ushort* __restrict__ WTu, ushort* rbase,
    const float* __restrict__ noise, const float* __restrict__ x,
    const float* __restrict__ bvec, const float* __restrict__ d2s,
    const float* __restrict__ w_out, const float* __restrict__ b_out,
    float* __restrict__ out, unsigned* bar)
{
  __shared__ ushort Blds[16*BROW/2];       // 127,232 B (WG240: w_out stage)
  __shared__ f32x4 red[5][2][64];          // 10,240 B
  __shared__ float pre_lds[32][16];        // 2,048 B
  const f16* WT = (const f16*)WTu;
  const int bid = blockIdx.x;
  const int tid = threadIdx.x;
  const int wv = tid>>6, l = tid&63, l15 = l&15, lh = l>>4;
  const int bh = wv&1, kw = wv>>1;         // kw 0..5
  const int kbase = (kw<4) ? kw*672 : (2688 + (kw-4)*640);
  const int nst   = (kw<4) ? 21 : 20;      // MFMA k-steps for this wave
  const int n0 = bid*16;
  const int ub = tid>>4, uc = tid&15;      // update: (batch, col), tid<512 only
  const int n  = n0 + uc;
  const float NS = 0.0063245553203367585f; // sqrt(2*0.2)*0.01

  // persistent per-thread state (tid<512: 1 column each)
  float hr=0.f, im=0.f, bv=0.f, dA=0.f, dB=0.f, al=0.f;
  bool cSR=false, cPFC=false, cME=false, dendF=false;
  if (bid < 240){
    if (tid < 512){
      bv = bvec[n];
      cSR  = (n0 < 512);
      cPFC = (n0 >= 1920 && n0 < 2432);
      cME  = (n0 >= 2432 && n0 < 3456);
      dendF = (n0>=512 && n0<1536) || cME;
      if (cSR){  dA=d2s[n];       dB=d2s[512+n]; }
      if (cPFC){ const int j=n-1920; dA=d2s[1024+j]; dB=d2s[1536+j]; }
      if (cME){
        const float LN10 = 2.302585092994046f;
        const float CEXP = 1.6989700043360187f/511.0f;
        const int j = n-2432;
        al = expf(-LN10*(1.0f + CEXP*(float)(j&511)));
      }
    }
    // ---- prologue: stage this WG's B-slice (16 rows x 3968 k) into LDS ----
    for (int c = tid; c < 16*496; c += 768){
      const int row = c / 496;
      const int kc  = c - row*496;
      f16x8 v = *(const f16x8*)(WT + (size_t)(n0+row)*KP + kc*8);
      *(f16x8*)((char*)Blds + row*BROW + kc*16) = v;
    }
  } else {
    // WG 240: stage w_out (512x3 f32) + b_out into Blds
    float* fB = (float*)Blds;
    for (int c = tid; c < 1536; c += 768) fB[c] = w_out[c];
    if (tid < 3) fB[1536+tid] = b_out[tid];
  }
  __syncthreads();

  // hierarchical barrier bookkeeping (monotonic epochs, no resets) — R9 design
  const int xg = bid & 7;
  const unsigned mycnt = (xg==0) ? 31u : 30u;
  unsigned* xcnt = bar + xg*32;            // per-group arrival (128B apart)
  unsigned* xep  = bar + 256 + xg*32;      // per-group epoch (release relay)
  unsigned* gcnt = bar + 512;              // global leader counter
  unsigned* gep  = bar + 544;              // global epoch

  // per-wave invariant LDS base for B
  const char* bb = (const char*)Blds + l15*BROW + kbase*2 + lh*16;

  for (int t=0; t<TSTEPS; t++){
    const ushort* rcu = rbase + (size_t)t*RSTRIDE;
    ushort*       rnu = rbase + (size_t)(t+1)*RSTRIDE;
    const f16* rc = (const f16*)rcu;

    if (bid < 240){
      // ---- prefetch update-phase operands (tid<512; hidden under MFMA) ----
      float nz_pf = 0.f, cA = 0.f, cB = 0.f;
      if (tid < 512){
        nz_pf = noise[(size_t)t*BATCH*NTOT + ub*NTOT + n];
        if (cSR){
          cA = h2f(rcu[ub*KP + 512 +n]); cB = h2f(rcu[ub*KP + 1024+n]);
        } else if (cPFC){
          const int j = n-1920;
          cA = h2f(rcu[ub*KP + 2432+j]); cB = h2f(rcu[ub*KP + 2944+j]);
        }
      }

      // ---- MFMA: 16 cols x 16 batch x (672|640)-K per wave; B from LDS ----
      f32x4 acc; acc.x=0.f; acc.y=0.f; acc.z=0.f; acc.w=0.f;
      {
        const f16* pa = rc + (size_t)(bh*16+l15)*KP + kbase + lh*8;
        #pragma unroll 4
        for (int ks=0; ks<nst; ks++){
          f16x8 a = *(const f16x8*)(pa + ks*32);
          f16x8 b = *(const f16x8*)(bb + ks*64);
          acc = __builtin_amdgcn_mfma_f32_16x16x32_f16(a, b, acc, 0,0,0);
        }
      }
      if (kw > 0) red[kw-1][bh][l] = acc;
      __syncthreads();
      if (kw == 0){
        #pragma unroll
        for (int w=0;w<5;w++) acc += red[w][bh][l];
        #pragma unroll
        for (int rg=0;rg<4;rg++)
          pre_lds[bh*16 + lh*4 + rg][l15] = acc[rg];
      }
      __syncthreads();

      // ---- update (tid<512): one (batch, col); r store agent-scope sc1 ----
      if (tid < 512){
        float p = pre_lds[ub][uc] + bv;
        p += cA*dA + cB*dB;
        if (cME){
          im = (1.f-al)*im + al*fmaxf(p,0.f); p += im;
        }
        hr = 0.8f*hr + 0.2f*p + NS*nz_pf;
        const float rv = dendF ? (1.f/(1.f+expf(-hr))) : fmaxf(hr,0.f);
        __hip_atomic_store(&rnu[ub*KP + n], f2h(rv),
                           __ATOMIC_RELAXED, __HIP_MEMORY_SCOPE_AGENT);
      }
    } else {
      // ---- WG 240: lane-parallel readout (weights from LDS) + x staging ----
      const float* fB = (const float*)Blds;
      if (wv < 3){
        #pragma unroll
        for (int q=0;q<32;q++){
          const int p = wv*32 + q;
          const int b = p/3, o = p%3;
          f16x8 rv8 = *(const f16x8*)(rc + (size_t)b*KP + l*8);
          float s = 0.f;
          #pragma unroll
          for (int i=0;i<8;i++) s += (float)rv8[i] * fB[(l*8+i)*3 + o];
          #pragma unroll
          for (int off=32; off; off>>=1) s += __shfl_down(s, off);
          if (l==0) out[t*BATCH*3 + b*3 + o] = s + fB[1536+o];
        }
      }
      if (t+1 < TSTEPS && tid < 256){
        const int b = tid>>3, j = (tid&7)*16;
        const float* xs = x + (size_t)(t+1)*BATCH*NIN + b*NIN + j;
        #pragma unroll
        for (int q=0;q<4;q++){
          float4 v = *(const float4*)(xs + q*4);
          uint u0 = (uint)f2h(v.x) | ((uint)f2h(v.y)<<16);
          uint u1 = (uint)f2h(v.z) | ((uint)f2h(v.w)<<16);
          uint* dst = (uint*)&rnu[b*KP + NTOT + j + q*4];
          __hip_atomic_store(dst,   u0, __ATOMIC_RELAXED, __HIP_MEMORY_SCOPE_AGENT);
          __hip_atomic_store(dst+1, u1, __ATOMIC_RELAXED, __HIP_MEMORY_SCOPE_AGENT);
        }
      }
    }

    // ---- hierarchical fence-free grid barrier (R9's proven design) ----
    if (t+1 < TSTEPS){
      __syncthreads();                       // drains vmcnt: sc1 stores at L3
      if (tid == 0){
        unsigned old = __hip_atomic_fetch_add(xcnt, 1u,
                          __ATOMIC_RELAXED, __HIP_MEMORY_SCOPE_AGENT);
        if (old == mycnt*(unsigned)(t+1) - 1u){
          // last WG of this group: arrive globally
          unsigned g = __hip_atomic_fetch_add(gcnt, 1u,
                          __ATOMIC_RELAXED, __HIP_MEMORY_SCOPE_AGENT);
          if (g == 8u*(unsigned)(t+1) - 1u){
            __hip_atomic_store(gep, (unsigned)(t+1),
                          __ATOMIC_RELAXED, __HIP_MEMORY_SCOPE_AGENT);
          } else {
            while (__hip_atomic_load(gep, __ATOMIC_RELAXED,
                          __HIP_MEMORY_SCOPE_AGENT) < (unsigned)(t+1))
              __builtin_amdgcn_s_sleep(2);
          }
          __hip_atomic_store(xep, (unsigned)(t+1),
                          __ATOMIC_RELAXED, __HIP_MEMORY_SCOPE_AGENT);
        } else {
          while (__hip_atomic_load(xep, __ATOMIC_RELAXED,
                          __HIP_MEMORY_SCOPE_AGENT) < (unsigned)(t+1))
            __builtin_amdgcn_s_sleep(2);
        }
        asm volatile("" ::: "memory");       // compiler barrier (no L2 inv needed)
      }
      __syncthreads();
    }
  }
}

extern "C" void kernel_launch(void* const* d_in, const int* in_sizes, int n_in,
                              void* d_out, int out_size, void* d_ws, size_t ws_size,
                              hipStream_t stream) {
  const float* x     = (const float*)d_in[0];   // [100,32,128]
  const float* noise = (const float*)d_in[1];   // [100,32,3840]
  const float* w_rec = (const float*)d_in[2];   // [3840,3840]
  const float* w_in  = (const float*)d_in[3];   // [128,3840]
  const float* bvec  = (const float*)d_in[4];   // [3840]
  const float* d2s   = (const float*)d_in[5];   // [2048]
  const float* w_out = (const float*)d_in[6];   // [512,3]
  const float* b_out = (const float*)d_in[7];   // [3]
  // d_in[8] = mask: derived analytically
  float* out = (float*)d_out;                   // [100,32,3]

  char* ws = (char*)d_ws;
  ushort*   WT    = (ushort*)(ws);              // 30,474,240 B
  ushort*   rbase = (ushort*)(ws + 30474240);   // 101 x 253,952 B = 25,649,152 B
  unsigned* bar   = (unsigned*)(ws + 56123392); //      4,096 B

  k_prep_w<<<3720,256,0,stream>>>(w_rec, w_in, WT);
  k_init<<<64,256,0,stream>>>(x, rbase, bar);
  k_run<<<NWG,768,0,stream>>>(WT, rbase, noise, x, bvec, d2s,
                              w_out, b_out, out, bar);
}

// Round 15
// 1006.956 us; speedup vs baseline: 3.8923x; 1.8071x over previous
//
#include <hip/hip_runtime.h>
#include <math.h>

typedef _Float16 f16;
typedef f16 f16x8 __attribute__((ext_vector_type(8)));
typedef float f32x4 __attribute__((ext_vector_type(4)));

#define NTOT 3840
#define KP   3968          // 3840 neurons + 128 inputs
#define BATCH 32
#define TSTEPS 100
#define NIN 128
#define NWG 241            // 240 col-tile WGs (16 cols, 512 thr) + 1 readout WG
#define RSTRIDE (BATCH*KP) // ushorts per r buffer (126,976)

__device__ __forceinline__ bool is_dend(int k){
  return (k>=512 && k<1536) || (k>=2432 && k<3456);
}
__device__ __forceinline__ bool is_inh(int k){
  return (k>=1536 && k<1920) || (k>=3456 && k<3840);
}
__device__ __forceinline__ ushort f2h(float v){ f16 h=(f16)v; return *(ushort*)&h; }
__device__ __forceinline__ float h2f(ushort u){ f16 h=*(f16*)&u; return (float)h; }

// ---------- one-time: WT[n][k] = fp16(w_eff^T), mask derived analytically ----------
__global__ __launch_bounds__(256) void k_prep_w(const float* __restrict__ w_rec,
    const float* __restrict__ w_in, ushort* __restrict__ WT){
  __shared__ ushort tile[64][72];
  const int bid = blockIdx.x;
  const int kt = bid / 60, nt = bid % 60;
  const int k0 = kt*64, n0 = nt*64;
  const int t = threadIdx.x;
  const int tr = t>>2, tq = t&3;
  const int k = k0 + tr;
  const int cbase = n0 + tq*16;
  if (k < NTOT){
    const float sgn = is_inh(k) ? -1.f : 1.f;
    const bool rowSr  = (k>=512  && k<1536);
    const bool rowPfc = (k>=2432 && k<3456);
    #pragma unroll
    for (int q=0;q<4;q++){
      float4 w = *(const float4*)(w_rec + (size_t)k*NTOT + cbase + q*4);
      float v[4] = {sgn*fabsf(w.x), sgn*fabsf(w.y), sgn*fabsf(w.z), sgn*fabsf(w.w)};
      #pragma unroll
      for (int e=0;e<4;e++){
        const int n = cbase + q*4 + e;
        if (n==k || (rowSr && n<512) || (rowPfc && n>=1920 && n<2432)) v[e]=0.f;
        tile[tr][tq*16+q*4+e] = f2h(v[e]);
      }
    }
  } else {
    const float* src = w_in + (size_t)(k-NTOT)*NTOT + cbase;
    #pragma unroll
    for (int q=0;q<4;q++){
      float4 w = *(const float4*)(src + q*4);
      tile[tr][tq*16+q*4+0] = f2h(w.x);
      tile[tr][tq*16+q*4+1] = f2h(w.y);
      tile[tr][tq*16+q*4+2] = f2h(w.z);
      tile[tr][tq*16+q*4+3] = f2h(w.w);
    }
  }
  __syncthreads();
  const int n  = n0 + tr;
  const int kq = tq*16;
  uint u[8];
  #pragma unroll
  for (int q=0;q<8;q++)
    u[q] = (uint)tile[kq+2*q][tr] | ((uint)tile[kq+2*q+1][tr] << 16);
  uint4* dst = (uint4*)(WT + (size_t)n*KP + k0 + kq);
  dst[0] = make_uint4(u[0],u[1],u[2],u[3]);
  dst[1] = make_uint4(u[4],u[5],u[6],u[7]);
}

// ---------- init: rbuf[0] (x_0 appended), barrier area zeroed ----------
__global__ void k_init(const float* __restrict__ x, ushort* __restrict__ r0,
                       unsigned* __restrict__ bar){
  int i = blockIdx.x*blockDim.x + threadIdx.x;
  int nthr = gridDim.x*blockDim.x;
  for (int e=i; e<1024; e+=nthr) bar[e] = 0u;
  for (int e=i; e<BATCH*KP; e+=nthr){
    int b = e / KP, k = e % KP;
    float v = (k<NTOT) ? (is_dend(k)?0.5f:0.f) : x[b*NIN + (k-NTOT)];
    r0[e] = f2h(v);
  }
}

// ---------- persistent kernel (R9 structure): 512 thr, B in LDS k-chunk-major ----------
// 241 WGs x 512 thr (8 waves, 2/SIMD). WG<240: 16 cols; wave (bh,kw) = batch-half x K/4.
// B layout: chunk (col, kc=k/8) at byte kc*256 + col*16 -> ds_read_b128 bank-start
// 4*l15 (16 starts x 2 lanes = conflict-free) instead of row-major's 8-way conflict.
__global__ __launch_bounds__(512,1) void k_run(
    const ushort* __restrict__ WTu, ushort* rbase,
    const float* __restrict__ noise, const float* __restrict__ x,
    const float* __restrict__ bvec, const float* __restrict__ d2s,
    const float* __restrict__ w_out, const float* __restrict__ b_out,
    float* __restrict__ out, unsigned* bar)
{
  __shared__ ushort Blds[63488];           // 126,976 B: 496 kc-chunks x 16 cols x 16B
  __shared__ f32x4 red[3][2][64];          // 6 KB
  __shared__ float pre_lds[32][16];        // 2 KB
  const f16* WT = (const f16*)WTu;
  const int bid = blockIdx.x;
  const int tid = threadIdx.x;
  const int wv = tid>>6, l = tid&63, l15 = l&15, lh = l>>4;
  const int bh = wv&1, kw = wv>>1;
  const int n0 = bid*16;
  const int ub = tid>>4, uc = tid&15;      // update: (batch, col)
  const int n  = n0 + uc;
  const float NS = 0.0063245553203367585f; // sqrt(2*0.2)*0.01

  // persistent per-thread state (1 column each)
  float hr=0.f, im=0.f, bv=0.f, dA=0.f, dB=0.f, al=0.f;
  bool cSR=false, cPFC=false, cME=false, dendF=false;
  if (bid < 240){
    bv = bvec[n];
    cSR  = (n0 < 512);
    cPFC = (n0 >= 1920 && n0 < 2432);
    cME  = (n0 >= 2432 && n0 < 3456);
    dendF = (n0>=512 && n0<1536) || cME;
    if (cSR){  dA=d2s[n];       dB=d2s[512+n]; }
    if (cPFC){ const int j=n-1920; dA=d2s[1024+j]; dB=d2s[1536+j]; }
    if (cME){
      const float LN10 = 2.302585092994046f;
      const float CEXP = 1.6989700043360187f/511.0f;  // (log10(5000)-2)/511
      const int j = n-2432;
      al = expf(-LN10*(1.0f + CEXP*(float)(j&511)));
    }
    // ---- prologue: stage B-slice into LDS, k-chunk-major ----
    for (int c = tid; c < 16*496; c += 512){
      const int row = c / 496;             // col 0..15
      const int kc  = c - row*496;         // k-chunk 0..495
      f16x8 v = *(const f16x8*)(WT + (size_t)(n0+row)*KP + kc*8);
      *(f16x8*)((char*)Blds + kc*256 + row*16) = v;
    }
  }

  // WG 240: preload w_out columns into registers (lane l covers rows l*8..l*8+7)
  float wo[3][8];
  float bo0=0.f, bo1=0.f, bo2=0.f;
  if (bid == 240){
    #pragma unroll
    for (int o=0;o<3;o++)
      #pragma unroll
      for (int i=0;i<8;i++) wo[o][i] = w_out[(l*8+i)*3 + o];
    bo0 = b_out[0]; bo1 = b_out[1]; bo2 = b_out[2];
  }
  __syncthreads();

  // hierarchical barrier bookkeeping (monotonic epochs, no resets)
  const int xg = bid & 7;                          // pseudo-XCD group
  const unsigned mycnt = (xg==0) ? 31u : 30u;      // WGs in this group
  unsigned* xcnt = bar + xg*32;                    // arrival counter (128B apart)
  unsigned* xep  = bar + 256 + xg*32;              // group epoch
  unsigned* gcnt = bar + 512;                      // global leader counter
  unsigned* gep  = bar + 544;                      // global epoch

  // per-wave invariant LDS base for B (k-chunk-major): chunk = kw*124 + ks*4 + lh
  const char* bb = (const char*)Blds + (kw*124 + lh)*256 + l15*16;

  for (int t=0; t<TSTEPS; t++){
    const ushort* rcu = rbase + (size_t)t*RSTRIDE;       // read: buffer t (fresh addrs)
    ushort*       rnu = rbase + (size_t)(t+1)*RSTRIDE;   // write: buffer t+1
    const f16* rc = (const f16*)rcu;

    if (bid < 240){
      // ---- prefetch update-phase operands (hide L3 latency under MFMA) ----
      const float nz_pf = noise[(size_t)t*BATCH*NTOT + ub*NTOT + n];
      float cA = 0.f, cB = 0.f;
      if (cSR){
        cA = h2f(rcu[ub*KP + 512 +n]); cB = h2f(rcu[ub*KP + 1024+n]);
      } else if (cPFC){
        const int j = n-1920;
        cA = h2f(rcu[ub*KP + 2432+j]); cB = h2f(rcu[ub*KP + 2944+j]);
      }

      // ---- MFMA: 16 cols x 16 batch rows x K/4 per wave; B from LDS ----
      f32x4 acc; acc.x=0.f; acc.y=0.f; acc.z=0.f; acc.w=0.f;
      {
        const f16* pa = rc + (size_t)(bh*16+l15)*KP + kw*992 + lh*8;
        #pragma unroll
        for (int ks=0; ks<31; ks++){
          f16x8 a = *(const f16x8*)(pa + ks*32);
          f16x8 b = *(const f16x8*)(bb + ks*1024);
          acc = __builtin_amdgcn_mfma_f32_16x16x32_f16(a, b, acc, 0,0,0);
        }
      }
      if (kw > 0) red[kw-1][bh][l] = acc;
      __syncthreads();
      if (kw == 0){
        #pragma unroll
        for (int w=0;w<3;w++) acc += red[w][bh][l];
        // C frag: col = l&15, row(batch within half) = (l>>4)*4 + reg
        #pragma unroll
        for (int rg=0;rg<4;rg++)
          pre_lds[bh*16 + lh*4 + rg][l15] = acc[rg];
      }
      __syncthreads();

      // ---- update: one (batch, col) per thread; r store is agent-scope (sc1) ----
      {
        float p = pre_lds[ub][uc] + bv;
        p += cA*dA + cB*dB;                       // zero for non-coupled cols
        if (cME){
          im = (1.f-al)*im + al*fmaxf(p,0.f); p += im;
        }
        hr = 0.8f*hr + 0.2f*p + NS*nz_pf;
        const float rv = dendF ? (1.f/(1.f+expf(-hr))) : fmaxf(hr,0.f);
        __hip_atomic_store(&rnu[ub*KP + n], f2h(rv),
                           __ATOMIC_RELAXED, __HIP_MEMORY_SCOPE_AGENT);
      }
    } else {
      // ---- WG 240: lane-parallel readout (overlaps others' matmul) ----
      // 96 (b,o) pairs over 8 waves = 12/wave; lane l covers k = l*8..l*8+7.
      #pragma unroll
      for (int q=0;q<12;q++){
        const int p = wv*12 + q;
        const int b = p/3, o = p%3;
        f16x8 rv8 = *(const f16x8*)(rc + (size_t)b*KP + l*8);
        float s = 0.f;
        #pragma unroll
        for (int i=0;i<8;i++) s += (float)rv8[i] * wo[o][i];
        #pragma unroll
        for (int off=32; off; off>>=1) s += __shfl_down(s, off);
        if (l==0){
          const float bo = (o==0)?bo0:((o==1)?bo1:bo2);
          out[t*BATCH*3 + b*3 + o] = s + bo;
        }
      }
      if (t+1 < TSTEPS && tid < 256){
        const int b = tid>>3, j = (tid&7)*16;
        const float* xs = x + (size_t)(t+1)*BATCH*NIN + b*NIN + j;
        #pragma unroll
        for (int q=0;q<4;q++){
          float4 v = *(const float4*)(xs + q*4);
          uint u0 = (uint)f2h(v.x) | ((uint)f2h(v.y)<<16);
          uint u1 = (uint)f2h(v.z) | ((uint)f2h(v.w)<<16);
          uint* dst = (uint*)&rnu[b*KP + NTOT + j + q*4];
          __hip_atomic_store(dst,   u0, __ATOMIC_RELAXED, __HIP_MEMORY_SCOPE_AGENT);
          __hip_atomic_store(dst+1, u1, __ATOMIC_RELAXED, __HIP_MEMORY_SCOPE_AGENT);
        }
      }
    }

    // ---- hierarchical fence-free grid barrier (skip after last step) ----
    if (t+1 < TSTEPS){
      __syncthreads();                       // drains vmcnt: sc1 stores at L3
      if (tid == 0){
        unsigned old = __hip_atomic_fetch_add(xcnt, 1u,
                          __ATOMIC_RELAXED, __HIP_MEMORY_SCOPE_AGENT);
        if (old == mycnt*(unsigned)(t+1) - 1u){
          // last WG of this group: arrive globally
          unsigned g = __hip_atomic_fetch_add(gcnt, 1u,
                          __ATOMIC_RELAXED, __HIP_MEMORY_SCOPE_AGENT);
          if (g == 8u*(unsigned)(t+1) - 1u){
            __hip_atomic_store(gep, (unsigned)(t+1),
                          __ATOMIC_RELAXED, __HIP_MEMORY_SCOPE_AGENT);
          } else {
            while (__hip_atomic_load(gep, __ATOMIC_RELAXED,
                          __HIP_MEMORY_SCOPE_AGENT) < (unsigned)(t+1))
              __builtin_amdgcn_s_sleep(2);
          }
          __hip_atomic_store(xep, (unsigned)(t+1),
                          __ATOMIC_RELAXED, __HIP_MEMORY_SCOPE_AGENT);
        } else {
          while (__hip_atomic_load(xep, __ATOMIC_RELAXED,
                          __HIP_MEMORY_SCOPE_AGENT) < (unsigned)(t+1))
            __builtin_amdgcn_s_sleep(2);
        }
        asm volatile("" ::: "memory");       // compiler barrier only (no L2 inv needed)
      }
      __syncthreads();
    }
  }
}

extern "C" void kernel_launch(void* const* d_in, const int* in_sizes, int n_in,
                              void* d_out, int out_size, void* d_ws, size_t ws_size,
                              hipStream_t stream) {
  const float* x     = (const float*)d_in[0];   // [100,32,128]
  const float* noise = (const float*)d_in[1];   // [100,32,3840]
  const float* w_rec = (const float*)d_in[2];   // [3840,3840]
  const float* w_in  = (const float*)d_in[3];   // [128,3840]
  const float* bvec  = (const float*)d_in[4];   // [3840]
  const float* d2s   = (const float*)d_in[5];   // [2048]
  const float* w_out = (const float*)d_in[6];   // [512,3]
  const float* b_out = (const float*)d_in[7];   // [3]
  // d_in[8] = mask: derived analytically
  float* out = (float*)d_out;                   // [100,32,3]

  char* ws = (char*)d_ws;
  ushort*   WT    = (ushort*)(ws);              // 30,474,240 B
  ushort*   rbase = (ushort*)(ws + 30474240);   // 101 x 253,952 B = 25,649,152 B
  unsigned* bar   = (unsigned*)(ws + 56123392); //      4,096 B

  k_prep_w<<<3720,256,0,stream>>>(w_rec, w_in, WT);
  k_init<<<64,256,0,stream>>>(x, rbase, bar);
  k_run<<<NWG,512,0,stream>>>(WT, rbase, noise, x, bvec, d2s,
                              w_out, b_out, out, bar);
}

// Round 16
// 964.659 us; speedup vs baseline: 4.0630x; 1.0438x over previous
//
#include <hip/hip_runtime.h>
#include <math.h>

typedef _Float16 f16;
typedef f16 f16x8 __attribute__((ext_vector_type(8)));
typedef float f32x4 __attribute__((ext_vector_type(4)));

#define NTOT 3840
#define KP   3968          // 3840 neurons + 128 inputs
#define BATCH 32
#define TSTEPS 100
#define NIN 128
#define NWG 241            // 240 col-tile WGs (16 cols, 512 thr) + 1 readout WG
#define RSTRIDE (BATCH*KP) // ushorts per r buffer (126,976)

__device__ __forceinline__ bool is_dend(int k){
  return (k>=512 && k<1536) || (k>=2432 && k<3456);
}
__device__ __forceinline__ bool is_inh(int k){
  return (k>=1536 && k<1920) || (k>=3456 && k<3840);
}
__device__ __forceinline__ ushort f2h(float v){ f16 h=(f16)v; return *(ushort*)&h; }
__device__ __forceinline__ float h2f(ushort u){ f16 h=*(f16*)&u; return (float)h; }

// ---------- one-time: WT[n][k] = fp16(w_eff^T), mask derived analytically ----------
__global__ __launch_bounds__(256) void k_prep_w(const float* __restrict__ w_rec,
    const float* __restrict__ w_in, ushort* __restrict__ WT){
  __shared__ ushort tile[64][72];
  const int bid = blockIdx.x;
  const int kt = bid / 60, nt = bid % 60;
  const int k0 = kt*64, n0 = nt*64;
  const int t = threadIdx.x;
  const int tr = t>>2, tq = t&3;
  const int k = k0 + tr;
  const int cbase = n0 + tq*16;
  if (k < NTOT){
    const float sgn = is_inh(k) ? -1.f : 1.f;
    const bool rowSr  = (k>=512  && k<1536);
    const bool rowPfc = (k>=2432 && k<3456);
    #pragma unroll
    for (int q=0;q<4;q++){
      float4 w = *(const float4*)(w_rec + (size_t)k*NTOT + cbase + q*4);
      float v[4] = {sgn*fabsf(w.x), sgn*fabsf(w.y), sgn*fabsf(w.z), sgn*fabsf(w.w)};
      #pragma unroll
      for (int e=0;e<4;e++){
        const int n = cbase + q*4 + e;
        if (n==k || (rowSr && n<512) || (rowPfc && n>=1920 && n<2432)) v[e]=0.f;
        tile[tr][tq*16+q*4+e] = f2h(v[e]);
      }
    }
  } else {
    const float* src = w_in + (size_t)(k-NTOT)*NTOT + cbase;
    #pragma unroll
    for (int q=0;q<4;q++){
      float4 w = *(const float4*)(src + q*4);
      tile[tr][tq*16+q*4+0] = f2h(w.x);
      tile[tr][tq*16+q*4+1] = f2h(w.y);
      tile[tr][tq*16+q*4+2] = f2h(w.z);
      tile[tr][tq*16+q*4+3] = f2h(w.w);
    }
  }
  __syncthreads();
  const int n  = n0 + tr;
  const int kq = tq*16;
  uint u[8];
  #pragma unroll
  for (int q=0;q<8;q++)
    u[q] = (uint)tile[kq+2*q][tr] | ((uint)tile[kq+2*q+1][tr] << 16);
  uint4* dst = (uint4*)(WT + (size_t)n*KP + k0 + kq);
  dst[0] = make_uint4(u[0],u[1],u[2],u[3]);
  dst[1] = make_uint4(u[4],u[5],u[6],u[7]);
}

// ---------- init: rbuf[0] (x_0 appended), barrier area zeroed ----------
__global__ void k_init(const float* __restrict__ x, ushort* __restrict__ r0,
                       unsigned* __restrict__ bar){
  int i = blockIdx.x*blockDim.x + threadIdx.x;
  int nthr = gridDim.x*blockDim.x;
  for (int e=i; e<1024; e+=nthr) bar[e] = 0u;
  for (int e=i; e<BATCH*KP; e+=nthr){
    int b = e / KP, k = e % KP;
    float v = (k<NTOT) ? (is_dend(k)?0.5f:0.f) : x[b*NIN + (k-NTOT)];
    r0[e] = f2h(v);
  }
}

// ---------- persistent kernel: 512 thr, B in LDS k-chunk-major, fused frag-update ----------
// 241 WGs x 512 thr (8 waves, 2/SIMD). WG<240: 16 cols; wave (bh,kw) = batch-half x K/4.
// kw==0 waves (tid<128) reduce partials AND apply the update directly in C-fragment
// layout (lane: col=l15, rows bh*16+lh*4+rg); h/ime persist in those lanes' registers.
// Single-hop barrier release: last arriver stores epoch to all 8 group lines.
__global__ __launch_bounds__(512,1) void k_run(
    const ushort* __restrict__ WTu, ushort* rbase,
    const float* __restrict__ noise, const float* __restrict__ x,
    const float* __restrict__ bvec, const float* __restrict__ d2s,
    const float* __restrict__ w_out, const float* __restrict__ b_out,
    float* __restrict__ out, unsigned* bar)
{
  __shared__ ushort Blds[63488];           // 126,976 B: 496 kc-chunks x 16 cols x 16B
  __shared__ f32x4 red[3][2][64];          // 6 KB
  const f16* WT = (const f16*)WTu;
  const int bid = blockIdx.x;
  const int tid = threadIdx.x;
  const int wv = tid>>6, l = tid&63, l15 = l&15, lh = l>>4;
  const int bh = wv&1, kw = wv>>1;
  const int n0 = bid*16;
  const int n  = n0 + l15;                 // update col for kw==0 lanes
  const int b0 = bh*16 + lh*4;             // first of 4 batch rows for kw==0 lanes
  const float NS = 0.0063245553203367585f; // sqrt(2*0.2)*0.01

  // persistent per-lane state (kw==0 waves only: 4 batch rows x 1 col)
  float hr[4] = {0.f,0.f,0.f,0.f};
  float im[4] = {0.f,0.f,0.f,0.f};
  float bv=0.f, dA=0.f, dB=0.f, al=0.f;
  bool cSR=false, cPFC=false, cME=false, dendF=false;
  if (bid < 240){
    if (kw == 0){
      bv = bvec[n];
      cSR  = (n0 < 512);
      cPFC = (n0 >= 1920 && n0 < 2432);
      cME  = (n0 >= 2432 && n0 < 3456);
      dendF = (n0>=512 && n0<1536) || cME;
      if (cSR){  dA=d2s[n];       dB=d2s[512+n]; }
      if (cPFC){ const int j=n-1920; dA=d2s[1024+j]; dB=d2s[1536+j]; }
      if (cME){
        const float LN10 = 2.302585092994046f;
        const float CEXP = 1.6989700043360187f/511.0f;  // (log10(5000)-2)/511
        const int j = n-2432;
        al = expf(-LN10*(1.0f + CEXP*(float)(j&511)));
      }
    }
    // ---- prologue: stage B-slice into LDS, k-chunk-major ----
    for (int c = tid; c < 16*496; c += 512){
      const int row = c / 496;             // col 0..15
      const int kc  = c - row*496;         // k-chunk 0..495
      f16x8 v = *(const f16x8*)(WT + (size_t)(n0+row)*KP + kc*8);
      *(f16x8*)((char*)Blds + kc*256 + row*16) = v;
    }
  }

  // WG 240: preload w_out columns into registers (lane l covers rows l*8..l*8+7)
  float wo[3][8];
  float bo0=0.f, bo1=0.f, bo2=0.f;
  if (bid == 240){
    #pragma unroll
    for (int o=0;o<3;o++)
      #pragma unroll
      for (int i=0;i<8;i++) wo[o][i] = w_out[(l*8+i)*3 + o];
    bo0 = b_out[0]; bo1 = b_out[1]; bo2 = b_out[2];
  }
  __syncthreads();

  // barrier bookkeeping (monotonic epochs, no resets)
  const int xg = bid & 7;                          // pseudo-XCD group
  const unsigned mycnt = (xg==0) ? 31u : 30u;      // WGs in this group
  unsigned* xcnt = bar + xg*32;                    // arrival counter (128B apart)
  unsigned* xep  = bar + 256 + xg*32;              // group epoch (release target)
  unsigned* gcnt = bar + 512;                      // global leader counter

  // per-wave invariant LDS base for B (k-chunk-major): chunk = kw*124 + ks*4 + lh
  const char* bb = (const char*)Blds + (kw*124 + lh)*256 + l15*16;

  for (int t=0; t<TSTEPS; t++){
    const ushort* rcu = rbase + (size_t)t*RSTRIDE;       // read: buffer t (fresh addrs)
    ushort*       rnu = rbase + (size_t)(t+1)*RSTRIDE;   // write: buffer t+1
    const f16* rc = (const f16*)rcu;

    if (bid < 240){
      // ---- prefetch update operands (kw==0 lanes; hidden under MFMA) ----
      float nz[4] = {0.f,0.f,0.f,0.f};
      float cA[4] = {0.f,0.f,0.f,0.f};
      float cB[4] = {0.f,0.f,0.f,0.f};
      if (kw == 0){
        #pragma unroll
        for (int rg=0;rg<4;rg++)
          nz[rg] = noise[(size_t)t*BATCH*NTOT + (b0+rg)*NTOT + n];
        if (cSR){
          #pragma unroll
          for (int rg=0;rg<4;rg++){
            cA[rg] = h2f(rcu[(b0+rg)*KP + 512 +n]);
            cB[rg] = h2f(rcu[(b0+rg)*KP + 1024+n]);
          }
        } else if (cPFC){
          const int j = n-1920;
          #pragma unroll
          for (int rg=0;rg<4;rg++){
            cA[rg] = h2f(rcu[(b0+rg)*KP + 2432+j]);
            cB[rg] = h2f(rcu[(b0+rg)*KP + 2944+j]);
          }
        }
      }

      // ---- MFMA: 16 cols x 16 batch rows x K/4 per wave; B from LDS ----
      f32x4 acc; acc.x=0.f; acc.y=0.f; acc.z=0.f; acc.w=0.f;
      {
        const f16* pa = rc + (size_t)(bh*16+l15)*KP + kw*992 + lh*8;
        #pragma unroll
        for (int ks=0; ks<31; ks++){
          f16x8 a = *(const f16x8*)(pa + ks*32);
          f16x8 b = *(const f16x8*)(bb + ks*1024);
          acc = __builtin_amdgcn_mfma_f32_16x16x32_f16(a, b, acc, 0,0,0);
        }
      }
      if (kw > 0) red[kw-1][bh][l] = acc;
      __syncthreads();
      if (kw == 0){
        #pragma unroll
        for (int w=0;w<3;w++) acc += red[w][bh][l];
        // fused update in C-frag layout: lane = (col l15, rows b0..b0+3)
        #pragma unroll
        for (int rg=0;rg<4;rg++){
          float p = acc[rg] + bv;
          p += cA[rg]*dA + cB[rg]*dB;              // zero for non-coupled cols
          if (cME){
            im[rg] = (1.f-al)*im[rg] + al*fmaxf(p,0.f); p += im[rg];
          }
          hr[rg] = 0.8f*hr[rg] + 0.2f*p + NS*nz[rg];
          const float rv = dendF ? (1.f/(1.f+expf(-hr[rg]))) : fmaxf(hr[rg],0.f);
          __hip_atomic_store(&rnu[(b0+rg)*KP + n], f2h(rv),
                             __ATOMIC_RELAXED, __HIP_MEMORY_SCOPE_AGENT);
        }
      }
    } else {
      // ---- WG 240: lane-parallel readout (overlaps others' matmul) ----
      // 96 (b,o) pairs over 8 waves = 12/wave; lane l covers k = l*8..l*8+7.
      #pragma unroll
      for (int q=0;q<12;q++){
        const int p = wv*12 + q;
        const int b = p/3, o = p%3;
        f16x8 rv8 = *(const f16x8*)(rc + (size_t)b*KP + l*8);
        float s = 0.f;
        #pragma unroll
        for (int i=0;i<8;i++) s += (float)rv8[i] * wo[o][i];
        #pragma unroll
        for (int off=32; off; off>>=1) s += __shfl_down(s, off);
        if (l==0){
          const float bo = (o==0)?bo0:((o==1)?bo1:bo2);
          out[t*BATCH*3 + b*3 + o] = s + bo;
        }
      }
      if (t+1 < TSTEPS && tid < 256){
        const int b = tid>>3, j = (tid&7)*16;
        const float* xs = x + (size_t)(t+1)*BATCH*NIN + b*NIN + j;
        #pragma unroll
        for (int q=0;q<4;q++){
          float4 v = *(const float4*)(xs + q*4);
          uint u0 = (uint)f2h(v.x) | ((uint)f2h(v.y)<<16);
          uint u1 = (uint)f2h(v.z) | ((uint)f2h(v.w)<<16);
          uint* dst = (uint*)&rnu[b*KP + NTOT + j + q*4];
          __hip_atomic_store(dst,   u0, __ATOMIC_RELAXED, __HIP_MEMORY_SCOPE_AGENT);
          __hip_atomic_store(dst+1, u1, __ATOMIC_RELAXED, __HIP_MEMORY_SCOPE_AGENT);
        }
      }
    }

    // ---- hierarchical fence-free barrier, single-hop release ----
    if (t+1 < TSTEPS){
      __syncthreads();                       // drains vmcnt: sc1 stores at L3
      if (tid == 0){
        unsigned old = __hip_atomic_fetch_add(xcnt, 1u,
                          __ATOMIC_RELAXED, __HIP_MEMORY_SCOPE_AGENT);
        if (old == mycnt*(unsigned)(t+1) - 1u){
          unsigned g = __hip_atomic_fetch_add(gcnt, 1u,
                          __ATOMIC_RELAXED, __HIP_MEMORY_SCOPE_AGENT);
          if (g == 8u*(unsigned)(t+1) - 1u){
            // last arriver releases ALL groups directly (single hop)
            #pragma unroll
            for (int grp=0; grp<8; grp++)
              __hip_atomic_store(bar + 256 + grp*32, (unsigned)(t+1),
                            __ATOMIC_RELAXED, __HIP_MEMORY_SCOPE_AGENT);
          }
        }
        while (__hip_atomic_load(xep, __ATOMIC_RELAXED,
                      __HIP_MEMORY_SCOPE_AGENT) < (unsigned)(t+1))
          __builtin_amdgcn_s_sleep(1);
        asm volatile("" ::: "memory");       // compiler barrier only (no L2 inv needed)
      }
      __syncthreads();
    }
  }
}

extern "C" void kernel_launch(void* const* d_in, const int* in_sizes, int n_in,
                              void* d_out, int out_size, void* d_ws, size_t ws_size,
                              hipStream_t stream) {
  const float* x     = (const float*)d_in[0];   // [100,32,128]
  const float* noise = (const float*)d_in[1];   // [100,32,3840]
  const float* w_rec = (const float*)d_in[2];   // [3840,3840]
  const float* w_in  = (const float*)d_in[3];   // [128,3840]
  const float* bvec  = (const float*)d_in[4];   // [3840]
  const float* d2s   = (const float*)d_in[5];   // [2048]
  const float* w_out = (const float*)d_in[6];   // [512,3]
  const float* b_out = (const float*)d_in[7];   // [3]
  // d_in[8] = mask: derived analytically
  float* out = (float*)d_out;                   // [100,32,3]

  char* ws = (char*)d_ws;
  ushort*   WT    = (ushort*)(ws);              // 30,474,240 B
  ushort*   rbase = (ushort*)(ws + 30474240);   // 101 x 253,952 B = 25,649,152 B
  unsigned* bar   = (unsigned*)(ws + 56123392); //      4,096 B

  k_prep_w<<<3720,256,0,stream>>>(w_rec, w_in, WT);
  k_init<<<64,256,0,stream>>>(x, rbase, bar);
  k_run<<<NWG,512,0,stream>>>(WT, rbase, noise, x, bvec, d2s,
                              w_out, b_out, out, bar);
}